// Round 10
// baseline (135.319 us; speedup 1.0000x reference)
//
#include <hip/hip_runtime.h>
#include <hip/hip_bf16.h>

#define NROWS 131072
#define KEXP 16
#define MPC 128
#define DIMD 64

typedef float f32x4  __attribute__((ext_vector_type(4)));
typedef float f32x16 __attribute__((ext_vector_type(16)));
typedef short s16x8  __attribute__((ext_vector_type(8)));

#define L2E 1.4426950408889634f
#define LN2 0.6931471805599453f

static __device__ inline unsigned int b2u(__hip_bfloat162 h) {
    union { __hip_bfloat162 h; unsigned int u; } c;
    c.h = h;
    return c.u;
}

static __device__ inline int4 cvt8s(float4 f0, float4 f1, float sc) {
    __hip_bfloat162 p0 = __float22bfloat162_rn(make_float2(f0.x * sc, f0.y * sc));
    __hip_bfloat162 p1 = __float22bfloat162_rn(make_float2(f0.z * sc, f0.w * sc));
    __hip_bfloat162 p2 = __float22bfloat162_rn(make_float2(f1.x * sc, f1.y * sc));
    __hip_bfloat162 p3 = __float22bfloat162_rn(make_float2(f1.z * sc, f1.w * sc));
    int4 pk;
    pk.x = (int)b2u(p0); pk.y = (int)b2u(p1); pk.z = (int)b2u(p2); pk.w = (int)b2u(p3);
    return pk;
}

// Single kernel, no prep. Block = 256 threads (4 waves), 256 rows, family of 4
// experts (wave w -> expert family*4+w). Each wave holds its expert's ENTIRE A
// in registers (16 frag chunks = 64 VGPR, converted from fp32 in prologue) plus
// bias chunks (A5, 16 VGPR; bias enters as 5th MFMA with constant-B ones).
// x is staged ONCE per block into LDS as B-frags (32 KB) with ONE barrier;
// blocks stream (2048 total) so inter-block occupancy provides all overlap —
// no k-loop, no double-buffer, no per-expert reloads.
// Per ntile (32 rows): 4 ds_read_b128 (shared across 4 mt) + 4x(5-MFMA chain ->
// 16 exp2) + one shfl_xor(32) + one atomicAdd (4-way across families).
__global__ __launch_bounds__(256, 3)
void fused_kernel(const float* __restrict__ x, const float* __restrict__ s,
                  const float* __restrict__ a, const float* __restrict__ b,
                  float* __restrict__ out) {
    __shared__ int4 xbuf[2048];   // 32 KB: [chunk(32)=nt*4+c][lane(64)]

    const int tid  = threadIdx.x;
    const int w    = tid >> 6;
    const int l    = tid & 63;
    const int ln   = l & 31;
    const int half = l >> 5;

    const int family = blockIdx.x & 3;
    const int r0     = (blockIdx.x >> 2) * 256;
    const int k      = family * 4 + w;

    // ---- persistent A fragments (64 VGPR): Afr[mt*4+c] lane l ->
    //      m = mt*32 + ln, d = c*16 + half*8 .. +7, value * log2e
    union { int4 i; s16x8 v; } Afr[16];
#pragma unroll
    for (int mt = 0; mt < 4; ++mt)
#pragma unroll
        for (int c = 0; c < 4; ++c) {
            const float* p = a + (size_t)(k * MPC + mt * 32 + ln) * DIMD + c * 16 + half * 8;
            Afr[mt * 4 + c].i = cvt8s(*(const float4*)(p), *(const float4*)(p + 4), L2E);
        }

    // ---- bias chunks (16 VGPR): A5[mt][m][k'=0] = b[k][mt*32+m]*log2e
    union { int4 i; s16x8 v; } A5[4];
#pragma unroll
    for (int mt = 0; mt < 4; ++mt) {
        A5[mt].i.x = 0; A5[mt].i.y = 0; A5[mt].i.z = 0; A5[mt].i.w = 0;
        if (half == 0) {
            union { __hip_bfloat16 h; unsigned short us; } cv;
            cv.h = __float2bfloat16(b[k * MPC + mt * 32 + ln] * L2E);
            A5[mt].i.x = (int)cv.us;   // element 0
        }
    }

    // constant ones-B for the bias MFMA: B[n][k'=0] = 1.0
    union { int4 i; s16x8 v; } Bones;
    Bones.i.x = (half == 0) ? 0x3F80 : 0;
    Bones.i.y = 0; Bones.i.z = 0; Bones.i.w = 0;

    const float sk2 = s[k] * LN2;

    // ---- stage 256 rows of x into LDS as B-frags (8 int4 per thread) ----
#pragma unroll
    for (int i = 0; i < 8; ++i) {
        const int u     = i * 256 + tid;
        const int chunk = u >> 6;            // nt*4 + c
        const int nt    = chunk >> 2;
        const int c     = chunk & 3;
        const int ll    = u & 63;
        const float* gp = x + (size_t)(r0 + nt * 32 + (ll & 31)) * DIMD
                            + c * 16 + (ll >> 5) * 8;
        xbuf[u] = cvt8s(*(const float4*)(gp), *(const float4*)(gp + 4), 1.0f);
    }
    __syncthreads();   // the ONLY barrier

    // ---- 8 n-tiles of 32 rows each ----
#pragma unroll 2
    for (int nt = 0; nt < 8; ++nt) {
        // B-frags for this ntile (conflict-free b128), reused across all 4 mt
        s16x8 Bx[4];
#pragma unroll
        for (int c = 0; c < 4; ++c)
            Bx[c] = *(const s16x8*)&xbuf[(nt * 4 + c) * 64 + l];

        float esum = 0.f;
#pragma unroll
        for (int mt = 0; mt < 4; ++mt) {
            f32x16 acc = {};
#pragma unroll
            for (int c = 0; c < 4; ++c)
                acc = __builtin_amdgcn_mfma_f32_32x32x16_bf16(Afr[mt * 4 + c].v, Bx[c], acc, 0, 0, 0);
            acc = __builtin_amdgcn_mfma_f32_32x32x16_bf16(A5[mt].v, Bones.v, acc, 0, 0, 0);

            float s0 = 0.f, s1 = 0.f, s2 = 0.f, s3 = 0.f;
#pragma unroll
            for (int r = 0; r < 4; ++r) {
                s0 += __builtin_amdgcn_exp2f(acc[4 * r + 0]);
                s1 += __builtin_amdgcn_exp2f(acc[4 * r + 1]);
                s2 += __builtin_amdgcn_exp2f(acc[4 * r + 2]);
                s3 += __builtin_amdgcn_exp2f(acc[4 * r + 3]);
            }
            esum += (s0 + s1) + (s2 + s3);
        }

        // combine the two m-halves (lanes l and l^32); row n = r0 + nt*32 + ln
        float tot = esum + __shfl_xor(esum, 32);
        if (half == 0)
            atomicAdd(&out[r0 + nt * 32 + ln], sk2 * __log2f(tot));
    }
}

extern "C" void kernel_launch(void* const* d_in, const int* in_sizes, int n_in,
                              void* d_out, int out_size, void* d_ws, size_t ws_size,
                              hipStream_t stream) {
    const float* x = (const float*)d_in[0];
    const float* s = (const float*)d_in[1];
    const float* a = (const float*)d_in[2];
    const float* b = (const float*)d_in[3];
    float* out = (float*)d_out;

    hipMemsetAsync(d_out, 0, (size_t)NROWS * sizeof(float), stream);
    fused_kernel<<<(NROWS / 256) * 4, 256, 0, stream>>>(x, s, a, b, out);
}

// Round 11
// 124.142 us; speedup vs baseline: 1.0900x; 1.0900x over previous
//
#include <hip/hip_runtime.h>
#include <hip/hip_bf16.h>

#define NROWS 131072
#define KEXP 16
#define MPC 128
#define DIMD 64

typedef float f32x4  __attribute__((ext_vector_type(4)));
typedef float f32x16 __attribute__((ext_vector_type(16)));
typedef short s16x8  __attribute__((ext_vector_type(8)));

#define L2E 1.4426950408889634f
#define LN2 0.6931471805599453f

static __device__ inline unsigned int b2u(__hip_bfloat162 h) {
    union { __hip_bfloat162 h; unsigned int u; } c;
    c.h = h;
    return c.u;
}

static __device__ inline int4 cvt8s(float4 f0, float4 f1, float sc) {
    __hip_bfloat162 p0 = __float22bfloat162_rn(make_float2(f0.x * sc, f0.y * sc));
    __hip_bfloat162 p1 = __float22bfloat162_rn(make_float2(f0.z * sc, f0.w * sc));
    __hip_bfloat162 p2 = __float22bfloat162_rn(make_float2(f1.x * sc, f1.y * sc));
    __hip_bfloat162 p3 = __float22bfloat162_rn(make_float2(f1.z * sc, f1.w * sc));
    int4 pk;
    pk.x = (int)b2u(p0); pk.y = (int)b2u(p1); pk.z = (int)b2u(p2); pk.w = (int)b2u(p3);
    return pk;
}

// async 16B/lane global->LDS DMA (wave-uniform LDS base + lane*16)
static __device__ inline void async_copy16(const void* g, void* l) {
    __builtin_amdgcn_global_load_lds(
        (const __attribute__((address_space(1))) unsigned int*)g,
        (__attribute__((address_space(3))) unsigned int*)l, 16, 0, 0);
}

// abff: per expert 20 chunks [mt(4)][c(5)] of 64 int4 (1 KB each) = 20 KB.
//   c<4 : A-frag, value j = a[k][mt*32 + (ul&31)][c*16 + (ul>>5)*8 + j] * L2E
//   c==4: bias chunk — A[m][k'=0] = b[k][mt*32+m] * L2E (ul<32, element 0), else 0
__global__ void prep_kernel(const float* __restrict__ a, const float* __restrict__ b,
                            short* __restrict__ abff) {
    const int u   = blockIdx.x * 256 + threadIdx.x;   // 0..20479
    const int k   = u / 1280;
    const int rem = u - k * 1280;
    const int mt  = rem / 320;
    const int rc  = rem - mt * 320;
    const int c   = rc >> 6;
    const int ul  = rc & 63;
    int4 pk;
    if (c < 4) {
        const float* p = a + (size_t)(k * MPC + mt * 32 + (ul & 31)) * DIMD
                           + c * 16 + (ul >> 5) * 8;
        pk = cvt8s(*(const float4*)(p), *(const float4*)(p + 4), L2E);
    } else {
        pk.x = 0; pk.y = 0; pk.z = 0; pk.w = 0;
        if (ul < 32) {
            union { __hip_bfloat16 h; unsigned short us; } cv;
            cv.h = __float2bfloat16(b[k * MPC + mt * 32 + ul] * L2E);
            pk.x = (int)cv.us;   // element 0 = bias, elements 1..7 = 0
        }
    }
    *(int4*)(abff + (size_t)u * 8) = pk;
}

// Round-7 structure + 2x grid oversubscription. Block = 256 threads (4 waves);
// wave owns 64 rows (2 n-tiles) of x persistent in registers (Bf[2][4], 32 VGPR).
// family = blockIdx&3 -> experts family*4..+3; grid = 2048 (8 nominal blocks
// per 4-LDS-slot CU -> dispatcher always has a ready block; fills occupancy
// jitter that capped round 7 at 29%).
// Per expert: extended A (4 data + 1 bias chunk per mtile) DMA'd global->LDS
// double-buffered (global_load_lds dwordx4, zero staging VALU). MFMA 32x32x16
// transposed (m on C-rows); bias rides as 5th MFMA (constant B = 1.0 at k'=0).
// Softmax m-sum in-lane + ONE shfl_xor(32)/ (expert,ntile).
// Families combine via atomicAdd (524k adds, ~free).
__global__ __launch_bounds__(256, 4)
void fused_kernel(const float* __restrict__ x, const float* __restrict__ s,
                  const short* __restrict__ abff, float* __restrict__ out) {
    __shared__ int4 abuf[2][1280];   // 2 x 20 KB

    const int tid  = threadIdx.x;
    const int w    = tid >> 6;
    const int l    = tid & 63;
    const int ln   = l & 31;
    const int half = l >> 5;

    const int family = blockIdx.x & 3;
    const int r0w    = (blockIdx.x >> 2) * 256 + w * 64;

    // persistent x B-fragments: Bf[nt][c] = x[r0w + nt*32 + ln][c*16 + half*8 ..+7]
    union { int4 i; s16x8 v; } Bf[2][4];
#pragma unroll
    for (int nt = 0; nt < 2; ++nt)
#pragma unroll
        for (int c = 0; c < 4; ++c) {
            const float* gp = x + (size_t)(r0w + nt * 32 + ln) * DIMD + c * 16 + half * 8;
            float4 f0 = *(const float4*)(gp);
            float4 f1 = *(const float4*)(gp + 4);
            Bf[nt][c].i = cvt8s(f0, f1, 1.0f);
        }

    // constant bias-B: B[n][k'=0] = 1.0 (k'=0 lives on half==0 lanes, element 0)
    union { int4 i; s16x8 v; } Bones;
    Bones.i.x = (half == 0) ? 0x3F80 : 0;   // bf16(1.0) in element 0
    Bones.i.y = 0; Bones.i.z = 0; Bones.i.w = 0;

    // DMA first expert into abuf[0]: wave w covers chunks w*5 .. w*5+4
    {
        const short* src = abff + (size_t)(family * 4) * 10240;
#pragma unroll
        for (int i = 0; i < 5; ++i) {
            const int ch = w * 5 + i;
            async_copy16(src + ch * 512 + l * 8, (char*)&abuf[0][0] + ch * 1024);
        }
    }
    __syncthreads();   // drains DMA

    float racc0 = 0.f, racc1 = 0.f;

    for (int k = 0; k < 4; ++k) {
        const int kf = family * 4 + k;
        const int kb = k & 1;

        // next expert's DMA into the other buffer (in flight during compute)
        if (k + 1 < 4) {
            const short* src = abff + (size_t)(kf + 1) * 10240;
#pragma unroll
            for (int i = 0; i < 5; ++i) {
                const int ch = w * 5 + i;
                async_copy16(src + ch * 512 + l * 8,
                             (char*)&abuf[kb ^ 1][0] + ch * 1024);
            }
        }

        const float sk2 = s[kf] * LN2;
        float esum0 = 0.f, esum1 = 0.f;

#pragma unroll
        for (int mt = 0; mt < 4; ++mt) {
            // A-frags incl. bias chunk (conflict-free b128: lane l -> l*16B)
            s16x8 Af[5];
#pragma unroll
            for (int c = 0; c < 5; ++c)
                Af[c] = *(const s16x8*)((const short*)&abuf[kb][0] + (mt * 5 + c) * 512 + l * 8);

            // ---- n-tile 0 chain ----
            {
                f32x16 acc = {};
#pragma unroll
                for (int c = 0; c < 4; ++c)
                    acc = __builtin_amdgcn_mfma_f32_32x32x16_bf16(Af[c], Bf[0][c].v, acc, 0, 0, 0);
                acc = __builtin_amdgcn_mfma_f32_32x32x16_bf16(Af[4], Bones.v, acc, 0, 0, 0);
                float s0 = 0.f, s1 = 0.f, s2 = 0.f, s3 = 0.f;
#pragma unroll
                for (int r = 0; r < 4; ++r) {
                    s0 += __builtin_amdgcn_exp2f(acc[4 * r + 0]);
                    s1 += __builtin_amdgcn_exp2f(acc[4 * r + 1]);
                    s2 += __builtin_amdgcn_exp2f(acc[4 * r + 2]);
                    s3 += __builtin_amdgcn_exp2f(acc[4 * r + 3]);
                }
                esum0 += (s0 + s1) + (s2 + s3);
            }
            // ---- n-tile 1 chain ----
            {
                f32x16 acc = {};
#pragma unroll
                for (int c = 0; c < 4; ++c)
                    acc = __builtin_amdgcn_mfma_f32_32x32x16_bf16(Af[c], Bf[1][c].v, acc, 0, 0, 0);
                acc = __builtin_amdgcn_mfma_f32_32x32x16_bf16(Af[4], Bones.v, acc, 0, 0, 0);
                float s0 = 0.f, s1 = 0.f, s2 = 0.f, s3 = 0.f;
#pragma unroll
                for (int r = 0; r < 4; ++r) {
                    s0 += __builtin_amdgcn_exp2f(acc[4 * r + 0]);
                    s1 += __builtin_amdgcn_exp2f(acc[4 * r + 1]);
                    s2 += __builtin_amdgcn_exp2f(acc[4 * r + 2]);
                    s3 += __builtin_amdgcn_exp2f(acc[4 * r + 3]);
                }
                esum1 += (s0 + s1) + (s2 + s3);
            }
        }

        // combine m-halves (lanes l and l^32), accumulate weighted lse
        float tot0 = esum0 + __shfl_xor(esum0, 32);
        float tot1 = esum1 + __shfl_xor(esum1, 32);
        racc0 = fmaf(sk2, __log2f(tot0), racc0);
        racc1 = fmaf(sk2, __log2f(tot1), racc1);

        __syncthreads();   // abuf[kb] free for reuse; next buffer drained
    }

    // half 0 lanes own n-tile 0 rows, half 1 lanes own n-tile 1 rows
    atomicAdd(&out[r0w + half * 32 + ln], half ? racc1 : racc0);
}

extern "C" void kernel_launch(void* const* d_in, const int* in_sizes, int n_in,
                              void* d_out, int out_size, void* d_ws, size_t ws_size,
                              hipStream_t stream) {
    const float* x = (const float*)d_in[0];
    const float* s = (const float*)d_in[1];
    const float* a = (const float*)d_in[2];
    const float* b = (const float*)d_in[3];
    float* out = (float*)d_out;

    short* abff = (short*)d_ws;   // 16 experts x 20 KB = 320 KB, frag-ordered

    hipMemsetAsync(d_out, 0, (size_t)NROWS * sizeof(float), stream);
    prep_kernel<<<80, 256, 0, stream>>>(a, b, abff);
    fused_kernel<<<(NROWS / 256) * 4, 256, 0, stream>>>(x, s, abff, out);
}